// Round 2
// baseline (87.425 us; speedup 1.0000x reference)
//
#include <hip/hip_runtime.h>

#define NB 16
#define NT 512
#define ND 384
#define MEL 2048
#define FPB 128            // frames per block
#define CPB (MEL / FPB)    // chunks per batch = 16 -> grid = 256 blocks (1/CU)
#define V4 (ND / 4)        // 96 float4 per row
#define PACE 1.0f

__global__ __launch_bounds__(512) void fp_regulate(const int* __restrict__ durations,
                                                   const float4* __restrict__ enc4,
                                                   float4* __restrict__ out4,
                                                   float* __restrict__ dec_out) {
    const int b = blockIdx.x / CPB;
    const int chunk = blockIdx.x % CPB;
    const int tid = threadIdx.x;

    __shared__ int cum[NT];      // inclusive cumsum of reps
    __shared__ int tok[FPB];     // token index per frame in this chunk (-1 = zero row)

    // ---- load durations + rep, scan in LDS (Hillis-Steele, 9 rounds) ----
    const int d = durations[b * NT + tid];
    const int rep = (int)floorf((float)d / PACE + 0.5f);
    cum[tid] = rep;
    __syncthreads();
    for (int off = 1; off < NT; off <<= 1) {
        const int tmp = (tid >= off) ? cum[tid - off] : 0;
        __syncthreads();
        cum[tid] += tmp;
        __syncthreads();
    }
    const int total = cum[NT - 1];

    // dec_lens: first chunk of each batch writes it
    if (chunk == 0 && tid == 0) {
        dec_out[b] = (float)(total < MEL ? total : MEL);
    }

    // ---- binary search: token for each frame in this chunk ----
    const int l0 = chunk * FPB;
    if (tid < FPB) {
        const int l = l0 + tid;
        int t = -1;
        if (l < total) {
            // smallest t with cum[t] > l  (zero-rep tokens skipped automatically)
            int lo = 0, hi = NT - 1;
            while (lo < hi) {
                const int mid = (lo + hi) >> 1;
                if (cum[mid] > l) hi = mid; else lo = mid + 1;
            }
            t = lo;
        }
        tok[tid] = t;
    }
    __syncthreads();

    // ---- stream the copy: FPB rows x 96 float4 ----
    const float4 zero = make_float4(0.f, 0.f, 0.f, 0.f);
    float4* __restrict__ dst = out4 + (size_t)(b * MEL + l0) * V4;
    const float4* __restrict__ src_b = enc4 + (size_t)b * NT * V4;
    #pragma unroll
    for (int e = tid; e < FPB * V4; e += 512) {
        const int f = e / V4;              // magic-mul, cheap
        const int v = e - f * V4;
        const int t = tok[f];
        dst[e] = (t >= 0) ? src_b[(size_t)t * V4 + v] : zero;
    }
}

extern "C" void kernel_launch(void* const* d_in, const int* in_sizes, int n_in,
                              void* d_out, int out_size, void* d_ws, size_t ws_size,
                              hipStream_t stream) {
    const int* durations = (const int*)d_in[0];
    const float* enc_out = (const float*)d_in[1];
    // d_in[2] is mel_max_len (=2048), compiled in as MEL

    float* out = (float*)d_out;
    float* dec_out = out + (size_t)NB * MEL * ND;   // dec_lens tail (as float)

    fp_regulate<<<NB * CPB, 512, 0, stream>>>(durations, (const float4*)enc_out,
                                              (float4*)out, dec_out);
}

// Round 4
// 87.002 us; speedup vs baseline: 1.0049x; 1.0049x over previous
//
#include <hip/hip_runtime.h>

#define NB 16
#define NT 512
#define ND 384
#define MEL 2048
#define FPB 64             // frames per block
#define CPB (MEL / FPB)    // 32 chunks per batch -> grid = 512 blocks (2/CU)
#define V4 (ND / 4)        // 96 float4 per row
#define PACE 1.0f

typedef float f32x4 __attribute__((ext_vector_type(4)));

__global__ __launch_bounds__(512) void fp_regulate(const int* __restrict__ durations,
                                                   const f32x4* __restrict__ enc4,
                                                   f32x4* __restrict__ out4,
                                                   float* __restrict__ dec_out) {
    const int b = blockIdx.x / CPB;
    const int chunk = blockIdx.x % CPB;
    const int tid = threadIdx.x;

    __shared__ int cum[NT];      // inclusive cumsum of reps
    __shared__ int tok[FPB];     // token index per frame in this chunk (-1 = zero row)

    // ---- load durations + rep, scan in LDS (Hillis-Steele, 9 rounds) ----
    const int d = durations[b * NT + tid];
    const int rep = (int)floorf((float)d / PACE + 0.5f);
    cum[tid] = rep;
    __syncthreads();
    for (int off = 1; off < NT; off <<= 1) {
        const int tmp = (tid >= off) ? cum[tid - off] : 0;
        __syncthreads();
        cum[tid] += tmp;
        __syncthreads();
    }
    const int total = cum[NT - 1];

    // dec_lens: first chunk of each batch writes it
    if (chunk == 0 && tid == 0) {
        dec_out[b] = (float)(total < MEL ? total : MEL);
    }

    // ---- binary search: token for each frame in this chunk ----
    const int l0 = chunk * FPB;
    if (tid < FPB) {
        const int l = l0 + tid;
        int t = -1;
        if (l < total) {
            // smallest t with cum[t] > l  (zero-rep tokens skipped automatically)
            int lo = 0, hi = NT - 1;
            while (lo < hi) {
                const int mid = (lo + hi) >> 1;
                if (cum[mid] > l) hi = mid; else lo = mid + 1;
            }
            t = lo;
        }
        tok[tid] = t;
    }
    __syncthreads();

    // ---- stream the copy: FPB rows x 96 float4, nontemporal stores ----
    const f32x4 zero = (f32x4)(0.f);
    f32x4* __restrict__ dst = out4 + (size_t)(b * MEL + l0) * V4;
    const f32x4* __restrict__ src_b = enc4 + (size_t)b * NT * V4;
    #pragma unroll
    for (int e = tid; e < FPB * V4; e += 512) {
        const int f = e / V4;
        const int v = e - f * V4;
        const int t = tok[f];
        const f32x4 r = (t >= 0) ? src_b[(size_t)t * V4 + v] : zero;
        __builtin_nontemporal_store(r, &dst[e]);
    }
}

extern "C" void kernel_launch(void* const* d_in, const int* in_sizes, int n_in,
                              void* d_out, int out_size, void* d_ws, size_t ws_size,
                              hipStream_t stream) {
    const int* durations = (const int*)d_in[0];
    const float* enc_out = (const float*)d_in[1];
    // d_in[2] is mel_max_len (=2048), compiled in as MEL

    float* out = (float*)d_out;
    float* dec_out = out + (size_t)NB * MEL * ND;   // dec_lens tail (as float)

    fp_regulate<<<NB * CPB, 512, 0, stream>>>(durations, (const f32x4*)enc_out,
                                              (f32x4*)out, dec_out);
}